// Round 1
// baseline (394.762 us; speedup 1.0000x reference)
//
#include <hip/hip_runtime.h>
#include <math.h>

#define KC 16
#define DF 256

// ws layout (floats)
#define WS_POOLED 0          // [16*256] S^T F accumulator
#define WS_CS     4096       // [16] cluster sizes
#define WS_M      4112       // [16] m_k = sum_e val*S[row][k]
#define WS_TR     4128       // trace accumulator
#define WS_ESUM   4129       // sum of edge_val (= 2*n_edges)
#define WS_TOTAL  4130

__global__ void zero_ws_kernel(float* __restrict__ ws) {
  int i = blockIdx.x * blockDim.x + threadIdx.x;
  if (i < WS_TOTAL) ws[i] = 0.0f;
}

// ---------------------------------------------------------------------------
// assignments = softmax(F @ W + b); also accumulates cluster_sizes.
// Wave processes 4 nodes per iteration. lane = q*16 + k (q = feature quarter,
// k = cluster). W kept transposed in LDS, row stride 257 (bank skew).
// ---------------------------------------------------------------------------
__global__ void __launch_bounds__(256) assign_kernel(
    const float* __restrict__ F, const float* __restrict__ W,
    const float* __restrict__ b, float* __restrict__ S,
    float* __restrict__ ws, int n) {
  __shared__ float Wt[KC * 257];
  __shared__ float cs_l[KC];
  const int t = threadIdx.x;
  for (int idx = t; idx < DF * KC; idx += 256) {
    int k = idx & 15, d = idx >> 4;       // W is [256][16] row-major
    Wt[k * 257 + d] = W[idx];
  }
  if (t < KC) cs_l[t] = 0.0f;
  __syncthreads();

  const int lane = t & 63;
  const int q = lane >> 4;
  const int k = lane & 15;
  const float* __restrict__ Wrow = &Wt[k * 257 + q * 64];
  const float bk = b[k];
  float cs_acc = 0.0f;

  const int wave = (blockIdx.x * 256 + t) >> 6;
  const int nwaves = gridDim.x * 4;

  for (int base = wave * 4; base < n; base += nwaves * 4) {
    float p[4] = {0.f, 0.f, 0.f, 0.f};
    const float* __restrict__ F0 = F + (size_t)base * DF + q * 64;
    #pragma unroll
    for (int j = 0; j < 16; ++j) {
      const float4 w4 = *(const float4*)(Wrow + 4 * j);
      #pragma unroll
      for (int nn = 0; nn < 4; ++nn) {
        const float4 f = *(const float4*)(F0 + (size_t)nn * DF + 4 * j);
        p[nn] += f.x * w4.x + f.y * w4.y + f.z * w4.z + f.w * w4.w;
      }
    }
    #pragma unroll
    for (int nn = 0; nn < 4; ++nn) {
      float lp = p[nn];
      lp += __shfl_xor(lp, 16);     // reduce over q
      lp += __shfl_xor(lp, 32);
      lp += bk;
      float mx = lp;                // softmax over the 16-lane k group
      mx = fmaxf(mx, __shfl_xor(mx, 1));
      mx = fmaxf(mx, __shfl_xor(mx, 2));
      mx = fmaxf(mx, __shfl_xor(mx, 4));
      mx = fmaxf(mx, __shfl_xor(mx, 8));
      float e = __expf(lp - mx);
      float sm = e;
      sm += __shfl_xor(sm, 1);
      sm += __shfl_xor(sm, 2);
      sm += __shfl_xor(sm, 4);
      sm += __shfl_xor(sm, 8);
      const float s = e / sm;
      if (lane < 16 && (base + nn) < n) {
        S[(size_t)(base + nn) * KC + k] = s;
        cs_acc += s;
      }
    }
  }
  if (lane < 16) atomicAdd(&cs_l[k], cs_acc);
  __syncthreads();
  if (t < KC) atomicAdd(&ws[WS_CS + t], cs_l[t]);
}

// ---------------------------------------------------------------------------
// Edge pass: trace(S^T A S), m_k = sum val*S[row][k], esum = sum val.
// ---------------------------------------------------------------------------
__global__ void __launch_bounds__(256) edge_kernel(
    const int* __restrict__ erow, const int* __restrict__ ecol,
    const float* __restrict__ evl, const float* __restrict__ S,
    float* __restrict__ ws, int ne) {
  __shared__ float red[KC + 2];
  const int t = threadIdx.x;
  if (t < KC + 2) red[t] = 0.0f;
  __syncthreads();

  float m[KC];
  #pragma unroll
  for (int i = 0; i < KC; ++i) m[i] = 0.f;
  float tr = 0.f, es = 0.f;

  const int stride = gridDim.x * blockDim.x;
  for (int e = blockIdx.x * blockDim.x + t; e < ne; e += stride) {
    const int r = erow[e];
    const int c = ecol[e];
    const float v = evl[e];
    const float4* __restrict__ Sr = (const float4*)(S + (size_t)r * KC);
    const float4* __restrict__ Sc = (const float4*)(S + (size_t)c * KC);
    const float4 a0 = Sr[0], a1 = Sr[1], a2 = Sr[2], a3 = Sr[3];
    const float4 b0 = Sc[0], b1 = Sc[1], b2 = Sc[2], b3 = Sc[3];
    float d = a0.x*b0.x + a0.y*b0.y + a0.z*b0.z + a0.w*b0.w
            + a1.x*b1.x + a1.y*b1.y + a1.z*b1.z + a1.w*b1.w
            + a2.x*b2.x + a2.y*b2.y + a2.z*b2.z + a2.w*b2.w
            + a3.x*b3.x + a3.y*b3.y + a3.z*b3.z + a3.w*b3.w;
    tr += v * d;
    es += v;
    m[0]  += v*a0.x; m[1]  += v*a0.y; m[2]  += v*a0.z; m[3]  += v*a0.w;
    m[4]  += v*a1.x; m[5]  += v*a1.y; m[6]  += v*a1.z; m[7]  += v*a1.w;
    m[8]  += v*a2.x; m[9]  += v*a2.y; m[10] += v*a2.z; m[11] += v*a2.w;
    m[12] += v*a3.x; m[13] += v*a3.y; m[14] += v*a3.z; m[15] += v*a3.w;
  }
  #pragma unroll
  for (int off = 1; off < 64; off <<= 1) {
    tr += __shfl_xor(tr, off);
    es += __shfl_xor(es, off);
    #pragma unroll
    for (int i = 0; i < KC; ++i) m[i] += __shfl_xor(m[i], off);
  }
  if ((t & 63) == 0) {
    atomicAdd(&red[KC], tr);
    atomicAdd(&red[KC + 1], es);
    #pragma unroll
    for (int i = 0; i < KC; ++i) atomicAdd(&red[i], m[i]);
  }
  __syncthreads();
  if (t < KC)            atomicAdd(&ws[WS_M + t], red[t]);
  else if (t == KC)      atomicAdd(&ws[WS_TR], red[KC]);
  else if (t == KC + 1)  atomicAdd(&ws[WS_ESUM], red[KC + 1]);
}

// ---------------------------------------------------------------------------
// pooled = S^T @ F (pre-division). Thread t owns feature column t; S rows are
// uniform-address reads (scalarizable); F reads fully coalesced.
// ---------------------------------------------------------------------------
__global__ void __launch_bounds__(256) pool_kernel(
    const float* __restrict__ F, const float* __restrict__ S,
    float* __restrict__ ws, int n) {
  const int t = threadIdx.x;
  float acc[KC];
  #pragma unroll
  for (int i = 0; i < KC; ++i) acc[i] = 0.f;

  const int nch = n >> 4;
  for (int ch = blockIdx.x; ch < nch; ch += gridDim.x) {
    const int base = ch << 4;
    #pragma unroll 4
    for (int nl = 0; nl < 16; ++nl) {
      const float f = F[(size_t)(base + nl) * DF + t];
      const float4* __restrict__ Sr = (const float4*)(S + (size_t)(base + nl) * KC);
      const float4 s0 = Sr[0], s1 = Sr[1], s2 = Sr[2], s3 = Sr[3];
      acc[0]  += f*s0.x; acc[1]  += f*s0.y; acc[2]  += f*s0.z; acc[3]  += f*s0.w;
      acc[4]  += f*s1.x; acc[5]  += f*s1.y; acc[6]  += f*s1.z; acc[7]  += f*s1.w;
      acc[8]  += f*s2.x; acc[9]  += f*s2.y; acc[10] += f*s2.z; acc[11] += f*s2.w;
      acc[12] += f*s3.x; acc[13] += f*s3.y; acc[14] += f*s3.z; acc[15] += f*s3.w;
    }
  }
  if (blockIdx.x == 0) {            // tail if n % 16 != 0
    for (int i2 = nch << 4; i2 < n; ++i2) {
      const float f = F[(size_t)i2 * DF + t];
      const float* __restrict__ Sr = S + (size_t)i2 * KC;
      #pragma unroll
      for (int kk = 0; kk < KC; ++kk) acc[kk] += f * Sr[kk];
    }
  }
  #pragma unroll
  for (int kk = 0; kk < KC; ++kk)
    atomicAdd(&ws[WS_POOLED + kk * DF + t], acc[kk]);
}

// ---------------------------------------------------------------------------
// Finalize: features_pooled = selu(pooled / cs), spectral & collapse losses.
// ---------------------------------------------------------------------------
__global__ void finalize_kernel(const float* __restrict__ ws,
                                float* __restrict__ out, int n) {
  const int t = threadIdx.x;
  const float alpha = 1.6732632423543772f;
  const float scale = 1.0507009873554805f;
  for (int idx = t; idx < KC * DF; idx += blockDim.x) {
    const int k = idx >> 8;
    const float x = ws[WS_POOLED + idx] / ws[WS_CS + k];
    const float r = x > 0.f ? x : alpha * expm1f(x);
    out[idx] = scale * r;
  }
  if (t == 0) {
    const float esum = ws[WS_ESUM];   // = 2 * n_edges
    const float tr = ws[WS_TR];
    float sm2 = 0.f, sc2 = 0.f;
    for (int i = 0; i < KC; ++i) {
      const float mi = ws[WS_M + i];
      sm2 += mi * mi;
      const float ci = ws[WS_CS + i];
      sc2 += ci * ci;
    }
    const float spectral = -(tr - sm2 / esum) / esum;
    const float collapse = 0.1f * (sqrtf(sc2) / (float)n * 4.0f - 1.0f);
    const size_t off = (size_t)(KC * DF) + (size_t)n * KC;
    out[off] = spectral;
    out[off + 1] = collapse;
  }
}

extern "C" void kernel_launch(void* const* d_in, const int* in_sizes, int n_in,
                              void* d_out, int out_size, void* d_ws, size_t ws_size,
                              hipStream_t stream) {
  const float* F   = (const float*)d_in[0];
  const float* W   = (const float*)d_in[1];
  const float* b   = (const float*)d_in[2];
  const int* erow  = (const int*)d_in[3];
  const int* ecol  = (const int*)d_in[4];
  const float* evl = (const float*)d_in[5];
  const int n  = in_sizes[0] / DF;
  const int ne = in_sizes[3];
  float* out = (float*)d_out;
  float* S   = out + KC * DF;      // assignments live directly in d_out
  float* ws  = (float*)d_ws;

  zero_ws_kernel<<<(WS_TOTAL + 255) / 256, 256, 0, stream>>>(ws);
  assign_kernel<<<2048, 256, 0, stream>>>(F, W, b, S, ws, n);
  edge_kernel<<<1024, 256, 0, stream>>>(erow, ecol, evl, S, ws, ne);
  pool_kernel<<<1024, 256, 0, stream>>>(F, S, ws, n);
  finalize_kernel<<<1, 256, 0, stream>>>(ws, out, n);
}

// Round 2
// 372.211 us; speedup vs baseline: 1.0606x; 1.0606x over previous
//
#include <hip/hip_runtime.h>
#include <math.h>

#define KC 16
#define DF 256

// ws layout (floats)
#define WS_POOLED 0          // [16*256] S^T F accumulator
#define WS_CS     4096       // [16] cluster sizes
#define WS_M      4112       // [16] m_k = sum_e val*S[row][k]
#define WS_TR     4128       // trace accumulator
#define WS_ESUM   4129       // sum of edge_val (= 2*n_edges)
#define WS_TOTAL  4130

__global__ void zero_ws_kernel(float* __restrict__ ws) {
  int i = blockIdx.x * blockDim.x + threadIdx.x;
  if (i < WS_TOTAL) ws[i] = 0.0f;
}

// ---------------------------------------------------------------------------
// assignments = softmax(F @ W + b); also accumulates cluster_sizes.
// Thread-per-node. F tile [256 nodes x 32 d] staged transposed in LDS
// (stride 257: conflict-free scalar reads, coalesced 128B global rows).
// W read via thread-uniform indices -> scalar loads (s_load), no LDS.
// ---------------------------------------------------------------------------
__global__ void __launch_bounds__(256) assign_kernel(
    const float* __restrict__ F, const float* __restrict__ W,
    const float* __restrict__ b, float* __restrict__ S,
    float* __restrict__ ws, int n) {
  __shared__ float Ft[32 * 257];
  __shared__ float cs_l[KC];
  const int t = threadIdx.x;
  if (t < KC) cs_l[t] = 0.0f;
  const int nb = blockIdx.x << 8;
  const int node = nb + t;
  const bool valid = node < n;

  float acc[KC];
  #pragma unroll
  for (int k = 0; k < KC; ++k) acc[k] = 0.f;

  for (int s = 0; s < 8; ++s) {
    // ---- stage 32 features of 256 nodes into LDS (transposed) ----
    #pragma unroll
    for (int it = 0; it < 8; ++it) {
      const int idx = t + (it << 8);     // 0..2047
      const int nl  = idx >> 3;          // node within tile
      const int jc  = idx & 7;           // float4 within 32-d row
      float4 f4 = make_float4(0.f, 0.f, 0.f, 0.f);
      if (nb + nl < n)
        f4 = *(const float4*)&F[(size_t)(nb + nl) * DF + (s << 5) + (jc << 2)];
      const int d0 = jc << 2;
      Ft[(d0 + 0) * 257 + nl] = f4.x;
      Ft[(d0 + 1) * 257 + nl] = f4.y;
      Ft[(d0 + 2) * 257 + nl] = f4.z;
      Ft[(d0 + 3) * 257 + nl] = f4.w;
    }
    __syncthreads();
    // ---- accumulate logits: W via uniform (scalar) loads ----
    #pragma unroll
    for (int j = 0; j < 8; ++j) {
      const float fv0 = Ft[(4 * j + 0) * 257 + t];
      const float fv1 = Ft[(4 * j + 1) * 257 + t];
      const float fv2 = Ft[(4 * j + 2) * 257 + t];
      const float fv3 = Ft[(4 * j + 3) * 257 + t];
      const float* __restrict__ Wg = &W[(size_t)((s << 5) + (j << 2)) * KC];
      #pragma unroll
      for (int k = 0; k < KC; ++k)
        acc[k] += fv0 * Wg[k] + fv1 * Wg[KC + k]
                + fv2 * Wg[2 * KC + k] + fv3 * Wg[3 * KC + k];
    }
    __syncthreads();
  }

  // ---- thread-local softmax ----
  float mx = -1e30f;
  #pragma unroll
  for (int k = 0; k < KC; ++k) { acc[k] += b[k]; mx = fmaxf(mx, acc[k]); }
  float sum = 0.f;
  #pragma unroll
  for (int k = 0; k < KC; ++k) { acc[k] = __expf(acc[k] - mx); sum += acc[k]; }
  const float inv = 1.0f / sum;
  #pragma unroll
  for (int k = 0; k < KC; ++k) acc[k] *= inv;
  if (!valid) {
    #pragma unroll
    for (int k = 0; k < KC; ++k) acc[k] = 0.f;
  }
  if (valid) {
    float4* __restrict__ So = (float4*)&S[(size_t)node * KC];
    So[0] = make_float4(acc[0],  acc[1],  acc[2],  acc[3]);
    So[1] = make_float4(acc[4],  acc[5],  acc[6],  acc[7]);
    So[2] = make_float4(acc[8],  acc[9],  acc[10], acc[11]);
    So[3] = make_float4(acc[12], acc[13], acc[14], acc[15]);
  }
  // ---- cluster sizes: wave butterfly -> LDS -> global ----
  #pragma unroll
  for (int off = 1; off < 64; off <<= 1) {
    #pragma unroll
    for (int k = 0; k < KC; ++k) acc[k] += __shfl_xor(acc[k], off);
  }
  if ((t & 63) == 0) {
    #pragma unroll
    for (int k = 0; k < KC; ++k) atomicAdd(&cs_l[k], acc[k]);
  }
  __syncthreads();
  if (t < KC) atomicAdd(&ws[WS_CS + t], cs_l[t]);
}

// ---------------------------------------------------------------------------
// Edge pass: trace(S^T A S), m_k = sum val*S[row][k], esum = sum val.
// ---------------------------------------------------------------------------
__global__ void __launch_bounds__(256) edge_kernel(
    const int* __restrict__ erow, const int* __restrict__ ecol,
    const float* __restrict__ evl, const float* __restrict__ S,
    float* __restrict__ ws, int ne) {
  __shared__ float red[KC + 2];
  const int t = threadIdx.x;
  if (t < KC + 2) red[t] = 0.0f;
  __syncthreads();

  float m[KC];
  #pragma unroll
  for (int i = 0; i < KC; ++i) m[i] = 0.f;
  float tr = 0.f, es = 0.f;

  const int stride = gridDim.x * blockDim.x;
  for (int e = blockIdx.x * blockDim.x + t; e < ne; e += stride) {
    const int r = erow[e];
    const int c = ecol[e];
    const float v = evl[e];
    const float4* __restrict__ Sr = (const float4*)(S + (size_t)r * KC);
    const float4* __restrict__ Sc = (const float4*)(S + (size_t)c * KC);
    const float4 a0 = Sr[0], a1 = Sr[1], a2 = Sr[2], a3 = Sr[3];
    const float4 b0 = Sc[0], b1 = Sc[1], b2 = Sc[2], b3 = Sc[3];
    float d = a0.x*b0.x + a0.y*b0.y + a0.z*b0.z + a0.w*b0.w
            + a1.x*b1.x + a1.y*b1.y + a1.z*b1.z + a1.w*b1.w
            + a2.x*b2.x + a2.y*b2.y + a2.z*b2.z + a2.w*b2.w
            + a3.x*b3.x + a3.y*b3.y + a3.z*b3.z + a3.w*b3.w;
    tr += v * d;
    es += v;
    m[0]  += v*a0.x; m[1]  += v*a0.y; m[2]  += v*a0.z; m[3]  += v*a0.w;
    m[4]  += v*a1.x; m[5]  += v*a1.y; m[6]  += v*a1.z; m[7]  += v*a1.w;
    m[8]  += v*a2.x; m[9]  += v*a2.y; m[10] += v*a2.z; m[11] += v*a2.w;
    m[12] += v*a3.x; m[13] += v*a3.y; m[14] += v*a3.z; m[15] += v*a3.w;
  }
  #pragma unroll
  for (int off = 1; off < 64; off <<= 1) {
    tr += __shfl_xor(tr, off);
    es += __shfl_xor(es, off);
    #pragma unroll
    for (int i = 0; i < KC; ++i) m[i] += __shfl_xor(m[i], off);
  }
  if ((t & 63) == 0) {
    atomicAdd(&red[KC], tr);
    atomicAdd(&red[KC + 1], es);
    #pragma unroll
    for (int i = 0; i < KC; ++i) atomicAdd(&red[i], m[i]);
  }
  __syncthreads();
  if (t < KC)            atomicAdd(&ws[WS_M + t], red[t]);
  else if (t == KC)      atomicAdd(&ws[WS_TR], red[KC]);
  else if (t == KC + 1)  atomicAdd(&ws[WS_ESUM], red[KC + 1]);
}

// ---------------------------------------------------------------------------
// pooled = S^T @ F (pre-division). Thread t owns feature column t; S rows are
// uniform-address reads (scalarizable); F reads fully coalesced.
// ---------------------------------------------------------------------------
__global__ void __launch_bounds__(256) pool_kernel(
    const float* __restrict__ F, const float* __restrict__ S,
    float* __restrict__ ws, int n) {
  const int t = threadIdx.x;
  float acc[KC];
  #pragma unroll
  for (int i = 0; i < KC; ++i) acc[i] = 0.f;

  const int nch = n >> 4;
  for (int ch = blockIdx.x; ch < nch; ch += gridDim.x) {
    const int base = ch << 4;
    #pragma unroll 4
    for (int nl = 0; nl < 16; ++nl) {
      const float f = F[(size_t)(base + nl) * DF + t];
      const float4* __restrict__ Sr = (const float4*)(S + (size_t)(base + nl) * KC);
      const float4 s0 = Sr[0], s1 = Sr[1], s2 = Sr[2], s3 = Sr[3];
      acc[0]  += f*s0.x; acc[1]  += f*s0.y; acc[2]  += f*s0.z; acc[3]  += f*s0.w;
      acc[4]  += f*s1.x; acc[5]  += f*s1.y; acc[6]  += f*s1.z; acc[7]  += f*s1.w;
      acc[8]  += f*s2.x; acc[9]  += f*s2.y; acc[10] += f*s2.z; acc[11] += f*s2.w;
      acc[12] += f*s3.x; acc[13] += f*s3.y; acc[14] += f*s3.z; acc[15] += f*s3.w;
    }
  }
  if (blockIdx.x == 0) {            // tail if n % 16 != 0
    for (int i2 = nch << 4; i2 < n; ++i2) {
      const float f = F[(size_t)i2 * DF + t];
      const float* __restrict__ Sr = S + (size_t)i2 * KC;
      #pragma unroll
      for (int kk = 0; kk < KC; ++kk) acc[kk] += f * Sr[kk];
    }
  }
  #pragma unroll
  for (int kk = 0; kk < KC; ++kk)
    atomicAdd(&ws[WS_POOLED + kk * DF + t], acc[kk]);
}

// ---------------------------------------------------------------------------
// Finalize: features_pooled = selu(pooled / cs), spectral & collapse losses.
// ---------------------------------------------------------------------------
__global__ void finalize_kernel(const float* __restrict__ ws,
                                float* __restrict__ out, int n) {
  const int t = threadIdx.x;
  const float alpha = 1.6732632423543772f;
  const float scale = 1.0507009873554805f;
  for (int idx = t; idx < KC * DF; idx += blockDim.x) {
    const int k = idx >> 8;
    const float x = ws[WS_POOLED + idx] / ws[WS_CS + k];
    const float r = x > 0.f ? x : alpha * expm1f(x);
    out[idx] = scale * r;
  }
  if (t == 0) {
    const float esum = ws[WS_ESUM];   // = 2 * n_edges
    const float tr = ws[WS_TR];
    float sm2 = 0.f, sc2 = 0.f;
    for (int i = 0; i < KC; ++i) {
      const float mi = ws[WS_M + i];
      sm2 += mi * mi;
      const float ci = ws[WS_CS + i];
      sc2 += ci * ci;
    }
    const float spectral = -(tr - sm2 / esum) / esum;
    const float collapse = 0.1f * (sqrtf(sc2) / (float)n * 4.0f - 1.0f);
    const size_t off = (size_t)(KC * DF) + (size_t)n * KC;
    out[off] = spectral;
    out[off + 1] = collapse;
  }
}

extern "C" void kernel_launch(void* const* d_in, const int* in_sizes, int n_in,
                              void* d_out, int out_size, void* d_ws, size_t ws_size,
                              hipStream_t stream) {
  const float* F   = (const float*)d_in[0];
  const float* W   = (const float*)d_in[1];
  const float* b   = (const float*)d_in[2];
  const int* erow  = (const int*)d_in[3];
  const int* ecol  = (const int*)d_in[4];
  const float* evl = (const float*)d_in[5];
  const int n  = in_sizes[0] / DF;
  const int ne = in_sizes[3];
  float* out = (float*)d_out;
  float* S   = out + KC * DF;      // assignments live directly in d_out
  float* ws  = (float*)d_ws;

  zero_ws_kernel<<<(WS_TOTAL + 255) / 256, 256, 0, stream>>>(ws);
  assign_kernel<<<(n + 255) / 256, 256, 0, stream>>>(F, W, b, S, ws, n);
  edge_kernel<<<2048, 256, 0, stream>>>(erow, ecol, evl, S, ws, ne);
  pool_kernel<<<2048, 256, 0, stream>>>(F, S, ws, n);
  finalize_kernel<<<1, 256, 0, stream>>>(ws, out, n);
}

// Round 3
// 330.683 us; speedup vs baseline: 1.1938x; 1.1256x over previous
//
#include <hip/hip_runtime.h>
#include <math.h>

#define KC 16
#define DF 256

// ws layout
#define WS_POOLED 0          // [16*256] S^T F accumulator (floats)
#define WS_CS     4096       // [16] cluster sizes
#define WS_M      4112       // [16] m_k = sum_e val*S[row][k]
#define WS_TR     4128       // trace accumulator
#define WS_ESUM   4129       // sum of edge_val (= 2*n_edges)
#define WS_TOTAL  4130
#define S16_OFF_BYTES 16640  // bf16 S shadow copy, 32 B/row, 16B-aligned

__global__ void zero_ws_kernel(float* __restrict__ ws) {
  int i = blockIdx.x * blockDim.x + threadIdx.x;
  if (i < WS_TOTAL) ws[i] = 0.0f;
}

__device__ __forceinline__ unsigned bf16_rne(float x) {
  unsigned u = __float_as_uint(x);
  return (u + 0x7fffu + ((u >> 16) & 1u)) >> 16;
}
__device__ __forceinline__ unsigned pack2(float lo, float hi) {
  return bf16_rne(lo) | (bf16_rne(hi) << 16);
}
__device__ __forceinline__ void cvt8(uint4 u, float* f) {
  f[0] = __uint_as_float(u.x << 16);
  f[1] = __uint_as_float(u.x & 0xffff0000u);
  f[2] = __uint_as_float(u.y << 16);
  f[3] = __uint_as_float(u.y & 0xffff0000u);
  f[4] = __uint_as_float(u.z << 16);
  f[5] = __uint_as_float(u.z & 0xffff0000u);
  f[6] = __uint_as_float(u.w << 16);
  f[7] = __uint_as_float(u.w & 0xffff0000u);
}

// ---------------------------------------------------------------------------
// assignments = softmax(F @ W + b) + cluster sizes + bf16 shadow of S.
// Thread-per-node; F staged transposed in LDS (stride 257); register
// double-buffer prefetch of the next 32-feature chunk hides global latency.
// W/b via thread-uniform (scalar) loads.
// ---------------------------------------------------------------------------
__global__ void __launch_bounds__(256) assign_kernel(
    const float* __restrict__ F, const float* __restrict__ W,
    const float* __restrict__ b, float* __restrict__ S,
    unsigned* __restrict__ S16, float* __restrict__ ws, int n) {
  __shared__ float Ft[32 * 257];
  __shared__ float cs_l[KC];
  const int t = threadIdx.x;
  if (t < KC) cs_l[t] = 0.0f;
  const int nb = blockIdx.x << 8;
  const int node = nb + t;
  const bool valid = node < n;
  const bool interior = (nb + 256 <= n);

  const int nl = t >> 3;          // staged node within tile (per 'it' offset)
  const int jc = t & 7;           // float4 slot within 32-feature row

  float4 pref[8];
  auto load_chunk = [&](int s) {
    #pragma unroll
    for (int it = 0; it < 8; ++it) {
      const int nn = nl + (it << 5);
      if (interior || nb + nn < n)
        pref[it] = *(const float4*)&F[(size_t)(nb + nn) * DF + (s << 5) + (jc << 2)];
      else
        pref[it] = make_float4(0.f, 0.f, 0.f, 0.f);
    }
  };

  float acc[KC];
  #pragma unroll
  for (int k = 0; k < KC; ++k) acc[k] = 0.f;

  load_chunk(0);
  for (int s = 0; s < 8; ++s) {
    __syncthreads();               // previous compute done: LDS reusable
    #pragma unroll
    for (int it = 0; it < 8; ++it) {
      const int nn = nl + (it << 5);
      const int d0 = jc << 2;
      Ft[(d0 + 0) * 257 + nn] = pref[it].x;
      Ft[(d0 + 1) * 257 + nn] = pref[it].y;
      Ft[(d0 + 2) * 257 + nn] = pref[it].z;
      Ft[(d0 + 3) * 257 + nn] = pref[it].w;
    }
    __syncthreads();
    if (s < 7) load_chunk(s + 1);  // in flight during compute below
    #pragma unroll
    for (int j = 0; j < 8; ++j) {
      const float fv0 = Ft[(4 * j + 0) * 257 + t];
      const float fv1 = Ft[(4 * j + 1) * 257 + t];
      const float fv2 = Ft[(4 * j + 2) * 257 + t];
      const float fv3 = Ft[(4 * j + 3) * 257 + t];
      const float* __restrict__ Wg = &W[(size_t)((s << 5) + (j << 2)) * KC];
      #pragma unroll
      for (int k = 0; k < KC; ++k)
        acc[k] += fv0 * Wg[k] + fv1 * Wg[KC + k]
                + fv2 * Wg[2 * KC + k] + fv3 * Wg[3 * KC + k];
    }
  }

  // thread-local softmax
  float mx = -1e30f;
  #pragma unroll
  for (int k = 0; k < KC; ++k) { acc[k] += b[k]; mx = fmaxf(mx, acc[k]); }
  float sum = 0.f;
  #pragma unroll
  for (int k = 0; k < KC; ++k) { acc[k] = __expf(acc[k] - mx); sum += acc[k]; }
  const float inv = 1.0f / sum;
  #pragma unroll
  for (int k = 0; k < KC; ++k) acc[k] *= inv;
  if (!valid) {
    #pragma unroll
    for (int k = 0; k < KC; ++k) acc[k] = 0.f;
  }
  if (valid) {
    float4* __restrict__ So = (float4*)&S[(size_t)node * KC];
    So[0] = make_float4(acc[0],  acc[1],  acc[2],  acc[3]);
    So[1] = make_float4(acc[4],  acc[5],  acc[6],  acc[7]);
    So[2] = make_float4(acc[8],  acc[9],  acc[10], acc[11]);
    So[3] = make_float4(acc[12], acc[13], acc[14], acc[15]);
    if (S16) {
      uint4* __restrict__ P = (uint4*)&S16[(size_t)node * 8];
      P[0] = make_uint4(pack2(acc[0], acc[1]),  pack2(acc[2], acc[3]),
                        pack2(acc[4], acc[5]),  pack2(acc[6], acc[7]));
      P[1] = make_uint4(pack2(acc[8], acc[9]),  pack2(acc[10], acc[11]),
                        pack2(acc[12], acc[13]), pack2(acc[14], acc[15]));
    }
  }
  // cluster sizes
  #pragma unroll
  for (int off = 1; off < 64; off <<= 1) {
    #pragma unroll
    for (int k = 0; k < KC; ++k) acc[k] += __shfl_xor(acc[k], off);
  }
  if ((t & 63) == 0) {
    #pragma unroll
    for (int k = 0; k < KC; ++k) atomicAdd(&cs_l[k], acc[k]);
  }
  __syncthreads();
  if (t < KC) atomicAdd(&ws[WS_CS + t], cs_l[t]);
}

// ---------------------------------------------------------------------------
// Edge pass (bf16 S): 4 edges per iteration, all loads issued before FMAs.
// ---------------------------------------------------------------------------
__device__ __forceinline__ void acc_edge(uint4 a0, uint4 a1, uint4 b0, uint4 b1,
                                         float v, float* m, float& tr, float& es) {
  float a[16], bb[16];
  cvt8(a0, a); cvt8(a1, a + 8); cvt8(b0, bb); cvt8(b1, bb + 8);
  float d = 0.f;
  #pragma unroll
  for (int k = 0; k < 16; ++k) d += a[k] * bb[k];
  tr += v * d;
  es += v;
  #pragma unroll
  for (int k = 0; k < 16; ++k) m[k] += v * a[k];
}

__global__ void __launch_bounds__(256) edge_kernel_bf16(
    const int* __restrict__ erow, const int* __restrict__ ecol,
    const float* __restrict__ evl, const uint4* __restrict__ S16,
    float* __restrict__ ws, int ne) {
  __shared__ float red[KC + 2];
  const int t = threadIdx.x;
  if (t < KC + 2) red[t] = 0.0f;
  __syncthreads();

  float m[KC];
  #pragma unroll
  for (int i = 0; i < KC; ++i) m[i] = 0.f;
  float tr = 0.f, es = 0.f;

  const int tid = blockIdx.x * 256 + t;
  const int stride = gridDim.x * 256;
  for (int e0 = tid; e0 < ne; e0 += 4 * stride) {
    const int eB = e0 + stride, eC = e0 + 2 * stride, eD = e0 + 3 * stride;
    int rA = erow[e0], cA = ecol[e0];
    float vA = evl[e0];
    int rB = 0, cB = 0, rC = 0, cC = 0, rD = 0, cD = 0;
    float vB = 0.f, vC = 0.f, vD = 0.f;
    if (eB < ne) { rB = erow[eB]; cB = ecol[eB]; vB = evl[eB]; }
    if (eC < ne) { rC = erow[eC]; cC = ecol[eC]; vC = evl[eC]; }
    if (eD < ne) { rD = erow[eD]; cD = ecol[eD]; vD = evl[eD]; }
    // issue all 16 gathers
    const uint4 a0A = S16[2*rA], a1A = S16[2*rA+1], b0A = S16[2*cA], b1A = S16[2*cA+1];
    const uint4 a0B = S16[2*rB], a1B = S16[2*rB+1], b0B = S16[2*cB], b1B = S16[2*cB+1];
    const uint4 a0C = S16[2*rC], a1C = S16[2*rC+1], b0C = S16[2*cC], b1C = S16[2*cC+1];
    const uint4 a0D = S16[2*rD], a1D = S16[2*rD+1], b0D = S16[2*cD], b1D = S16[2*cD+1];
    acc_edge(a0A, a1A, b0A, b1A, vA, m, tr, es);
    acc_edge(a0B, a1B, b0B, b1B, vB, m, tr, es);
    acc_edge(a0C, a1C, b0C, b1C, vC, m, tr, es);
    acc_edge(a0D, a1D, b0D, b1D, vD, m, tr, es);
  }
  #pragma unroll
  for (int off = 1; off < 64; off <<= 1) {
    tr += __shfl_xor(tr, off);
    es += __shfl_xor(es, off);
    #pragma unroll
    for (int i = 0; i < KC; ++i) m[i] += __shfl_xor(m[i], off);
  }
  if ((t & 63) == 0) {
    atomicAdd(&red[KC], tr);
    atomicAdd(&red[KC + 1], es);
    #pragma unroll
    for (int i = 0; i < KC; ++i) atomicAdd(&red[i], m[i]);
  }
  __syncthreads();
  if (t < KC)            atomicAdd(&ws[WS_M + t], red[t]);
  else if (t == KC)      atomicAdd(&ws[WS_TR], red[KC]);
  else if (t == KC + 1)  atomicAdd(&ws[WS_ESUM], red[KC + 1]);
}

// fp32 fallback (ws too small for the bf16 shadow)
__global__ void __launch_bounds__(256) edge_kernel_f32(
    const int* __restrict__ erow, const int* __restrict__ ecol,
    const float* __restrict__ evl, const float* __restrict__ S,
    float* __restrict__ ws, int ne) {
  __shared__ float red[KC + 2];
  const int t = threadIdx.x;
  if (t < KC + 2) red[t] = 0.0f;
  __syncthreads();
  float m[KC];
  #pragma unroll
  for (int i = 0; i < KC; ++i) m[i] = 0.f;
  float tr = 0.f, es = 0.f;
  const int stride = gridDim.x * blockDim.x;
  for (int e = blockIdx.x * blockDim.x + t; e < ne; e += stride) {
    const int r = erow[e];
    const int c = ecol[e];
    const float v = evl[e];
    const float4* __restrict__ Sr = (const float4*)(S + (size_t)r * KC);
    const float4* __restrict__ Sc = (const float4*)(S + (size_t)c * KC);
    const float4 a0 = Sr[0], a1 = Sr[1], a2 = Sr[2], a3 = Sr[3];
    const float4 b0 = Sc[0], b1 = Sc[1], b2 = Sc[2], b3 = Sc[3];
    float d = a0.x*b0.x + a0.y*b0.y + a0.z*b0.z + a0.w*b0.w
            + a1.x*b1.x + a1.y*b1.y + a1.z*b1.z + a1.w*b1.w
            + a2.x*b2.x + a2.y*b2.y + a2.z*b2.z + a2.w*b2.w
            + a3.x*b3.x + a3.y*b3.y + a3.z*b3.z + a3.w*b3.w;
    tr += v * d; es += v;
    m[0]+=v*a0.x; m[1]+=v*a0.y; m[2]+=v*a0.z; m[3]+=v*a0.w;
    m[4]+=v*a1.x; m[5]+=v*a1.y; m[6]+=v*a1.z; m[7]+=v*a1.w;
    m[8]+=v*a2.x; m[9]+=v*a2.y; m[10]+=v*a2.z; m[11]+=v*a2.w;
    m[12]+=v*a3.x; m[13]+=v*a3.y; m[14]+=v*a3.z; m[15]+=v*a3.w;
  }
  #pragma unroll
  for (int off = 1; off < 64; off <<= 1) {
    tr += __shfl_xor(tr, off);
    es += __shfl_xor(es, off);
    #pragma unroll
    for (int i = 0; i < KC; ++i) m[i] += __shfl_xor(m[i], off);
  }
  if ((t & 63) == 0) {
    atomicAdd(&red[KC], tr);
    atomicAdd(&red[KC + 1], es);
    #pragma unroll
    for (int i = 0; i < KC; ++i) atomicAdd(&red[i], m[i]);
  }
  __syncthreads();
  if (t < KC)            atomicAdd(&ws[WS_M + t], red[t]);
  else if (t == KC)      atomicAdd(&ws[WS_TR], red[KC]);
  else if (t == KC + 1)  atomicAdd(&ws[WS_ESUM], red[KC + 1]);
}

// ---------------------------------------------------------------------------
// pooled = S^T @ F. Thread owns feature column t; 32 register-staged F loads
// per chunk before the FMA block (MLP); S rows are uniform -> scalar loads.
// ---------------------------------------------------------------------------
__global__ void __launch_bounds__(256) pool_kernel(
    const float* __restrict__ F, const float* __restrict__ S,
    float* __restrict__ ws, int n) {
  const int t = threadIdx.x;
  float acc[KC];
  #pragma unroll
  for (int i = 0; i < KC; ++i) acc[i] = 0.f;

  const int nch = n >> 5;
  for (int ch = blockIdx.x; ch < nch; ch += gridDim.x) {
    const int base = ch << 5;
    float fl[32];
    #pragma unroll
    for (int i = 0; i < 32; ++i)
      fl[i] = F[(size_t)(base + i) * DF + t];
    #pragma unroll
    for (int i = 0; i < 32; ++i) {
      const float4* __restrict__ Sr = (const float4*)(S + (size_t)(base + i) * KC);
      const float4 s0 = Sr[0], s1 = Sr[1], s2 = Sr[2], s3 = Sr[3];
      const float f = fl[i];
      acc[0]+=f*s0.x;  acc[1]+=f*s0.y;  acc[2]+=f*s0.z;  acc[3]+=f*s0.w;
      acc[4]+=f*s1.x;  acc[5]+=f*s1.y;  acc[6]+=f*s1.z;  acc[7]+=f*s1.w;
      acc[8]+=f*s2.x;  acc[9]+=f*s2.y;  acc[10]+=f*s2.z; acc[11]+=f*s2.w;
      acc[12]+=f*s3.x; acc[13]+=f*s3.y; acc[14]+=f*s3.z; acc[15]+=f*s3.w;
    }
  }
  if (blockIdx.x == 0) {                 // tail (n % 32)
    for (int i2 = nch << 5; i2 < n; ++i2) {
      const float f = F[(size_t)i2 * DF + t];
      const float* __restrict__ Sr = S + (size_t)i2 * KC;
      #pragma unroll
      for (int kk = 0; kk < KC; ++kk) acc[kk] += f * Sr[kk];
    }
  }
  #pragma unroll
  for (int kk = 0; kk < KC; ++kk)
    atomicAdd(&ws[WS_POOLED + kk * DF + t], acc[kk]);
}

__global__ void finalize_kernel(const float* __restrict__ ws,
                                float* __restrict__ out, int n) {
  const int t = threadIdx.x;
  const float alpha = 1.6732632423543772f;
  const float scale = 1.0507009873554805f;
  for (int idx = t; idx < KC * DF; idx += blockDim.x) {
    const int k = idx >> 8;
    const float x = ws[WS_POOLED + idx] / ws[WS_CS + k];
    const float r = x > 0.f ? x : alpha * expm1f(x);
    out[idx] = scale * r;
  }
  if (t == 0) {
    const float esum = ws[WS_ESUM];   // = 2 * n_edges
    const float tr = ws[WS_TR];
    float sm2 = 0.f, sc2 = 0.f;
    for (int i = 0; i < KC; ++i) {
      const float mi = ws[WS_M + i];
      sm2 += mi * mi;
      const float ci = ws[WS_CS + i];
      sc2 += ci * ci;
    }
    const float spectral = -(tr - sm2 / esum) / esum;
    const float collapse = 0.1f * (sqrtf(sc2) / (float)n * 4.0f - 1.0f);
    const size_t off = (size_t)(KC * DF) + (size_t)n * KC;
    out[off] = spectral;
    out[off + 1] = collapse;
  }
}

extern "C" void kernel_launch(void* const* d_in, const int* in_sizes, int n_in,
                              void* d_out, int out_size, void* d_ws, size_t ws_size,
                              hipStream_t stream) {
  const float* F   = (const float*)d_in[0];
  const float* W   = (const float*)d_in[1];
  const float* b   = (const float*)d_in[2];
  const int* erow  = (const int*)d_in[3];
  const int* ecol  = (const int*)d_in[4];
  const float* evl = (const float*)d_in[5];
  const int n  = in_sizes[0] / DF;
  const int ne = in_sizes[3];
  float* out = (float*)d_out;
  float* S   = out + KC * DF;      // assignments live directly in d_out
  float* ws  = (float*)d_ws;

  const bool use_bf16 = ws_size >= (size_t)S16_OFF_BYTES + (size_t)n * KC * 2 + 64;
  unsigned* S16 = use_bf16 ? (unsigned*)((char*)d_ws + S16_OFF_BYTES) : nullptr;

  zero_ws_kernel<<<(WS_TOTAL + 255) / 256, 256, 0, stream>>>(ws);
  assign_kernel<<<(n + 255) / 256, 256, 0, stream>>>(F, W, b, S, S16, ws, n);
  if (use_bf16)
    edge_kernel_bf16<<<1024, 256, 0, stream>>>(erow, ecol, evl, (const uint4*)S16, ws, ne);
  else
    edge_kernel_f32<<<2048, 256, 0, stream>>>(erow, ecol, evl, S, ws, ne);
  pool_kernel<<<1024, 256, 0, stream>>>(F, S, ws, n);
  finalize_kernel<<<1, 256, 0, stream>>>(ws, out, n);
}